// Round 1
// baseline (1043.942 us; speedup 1.0000x reference)
//
#include <hip/hip_runtime.h>
#include <cstdint>
#include <cstddef>

#define B_   64
#define T_   256
#define DIN_ 128
#define H_   256
#define G3_  768   // 3*H

// ---------- helpers ----------
__device__ __forceinline__ unsigned short f2bf(float f) {
  unsigned u = __float_as_uint(f);
  unsigned r = u + 0x7fffu + ((u >> 16) & 1u);   // RNE (weights/h are finite & normal)
  return (unsigned short)(r >> 16);
}

// acc += dot(v2bf16(a), v2bf16(b)) in fp32  (V_DOT2_F32_BF16, CDNA3/4)
__device__ __forceinline__ void dot2bf(float& acc, unsigned a, unsigned b) {
  asm("v_dot2_f32_bf16 %0, %1, %2, %0" : "+v"(acc) : "v"(a), "v"(b));
}

// ---------- prep: transpose W_ih, concat head weights, repack W_hh to bf16 ----------
__global__ __launch_bounds__(256) void prep_kernel(
    const float* __restrict__ W_ih, const float* __restrict__ W_hh,
    const float* __restrict__ W_mz, const float* __restrict__ W_mx,
    const float* __restrict__ W_pz, const float* __restrict__ W_cx,
    float* __restrict__ WT_ih, float* __restrict__ WheadT,
    unsigned* __restrict__ Wreg) {
  int i = blockIdx.x * 256 + threadIdx.x;
  if (i < 98304) {                       // WT_ih[k*768+g] = W_ih[g*128+k]
    int k = i / 768, g = i % 768;
    WT_ih[i] = W_ih[g * 128 + k];
  } else if (i < 98304 + 24576) {        // WheadT[k*96+c]
    int j = i - 98304;
    int k = j / 96, c = j % 96;
    float v;
    if (c < 8)       v = W_mz[c * 256 + k];
    else if (c < 16) v = W_mx[(c - 8) * 256 + k];
    else if (c < 32) v = W_pz[(c - 16) * 256 + k];
    else             v = W_cx[(c - 32) * 256 + k];
    WheadT[j] = v;
  } else {                               // bf16-pair repack of W_hh for gru reg preload
    int m = i - 122880;                  // 0..98303
    int u = m % 256, jl = m / 256;       // jl = r*128 + jj, r=gate(0:r,1:z,2:n), jj=k-pair
    int r = jl >> 7, jj = jl & 127;
    int row = r * 256 + u;               // W_hh row for this thread's gate
    unsigned short lo = f2bf(W_hh[row * 256 + 2 * jj]);
    unsigned short hi = f2bf(W_hh[row * 256 + 2 * jj + 1]);
    unsigned f = ((unsigned)(jl >> 2) * 256u + (unsigned)u) * 4u + (unsigned)(jl & 3);
    Wreg[f] = ((unsigned)hi << 16) | (unsigned)lo;
  }
}

// ---------- x_proj = y @ W_ih^T + b_ih : [16384,128]x[128,768] fp32 ----------
__global__ __launch_bounds__(256) void xproj_kernel(
    const float* __restrict__ y, const float* __restrict__ WT_ih,
    const float* __restrict__ b_ih, float* __restrict__ xp) {
  __shared__ float ylds[64][132];        // +4 pad: 2-way (free) bank aliasing only
  int tid = threadIdx.x;
  int row0 = blockIdx.x * 64;
  const float4* y4 = (const float4*)(y + (size_t)row0 * DIN_);
#pragma unroll
  for (int i = 0; i < 8; ++i) {
    int idx = i * 256 + tid;             // 2048 float4 = 64x128
    float4 v = y4[idx];
    int r = idx >> 5, c4 = (idx & 31) * 4;
    ylds[r][c4 + 0] = v.x; ylds[r][c4 + 1] = v.y;
    ylds[r][c4 + 2] = v.z; ylds[r][c4 + 3] = v.w;
  }
  __syncthreads();
  int tx = tid & 15, ty = tid >> 4;      // 16x16 threads; thread: 4 rows x 8 cols
  for (int c = 0; c < 6; ++c) {
    int col0 = c * 128 + tx * 8;
    float acc[4][8];
#pragma unroll
    for (int a = 0; a < 4; ++a)
#pragma unroll
      for (int b = 0; b < 8; ++b) acc[a][b] = 0.f;
#pragma unroll 4
    for (int k = 0; k < 128; ++k) {
      float4 w0 = *(const float4*)&WT_ih[k * 768 + col0];
      float4 w1 = *(const float4*)&WT_ih[k * 768 + col0 + 4];
      float a0 = ylds[ty * 4 + 0][k], a1 = ylds[ty * 4 + 1][k];
      float a2 = ylds[ty * 4 + 2][k], a3 = ylds[ty * 4 + 3][k];
      acc[0][0] += a0 * w0.x; acc[0][1] += a0 * w0.y; acc[0][2] += a0 * w0.z; acc[0][3] += a0 * w0.w;
      acc[0][4] += a0 * w1.x; acc[0][5] += a0 * w1.y; acc[0][6] += a0 * w1.z; acc[0][7] += a0 * w1.w;
      acc[1][0] += a1 * w0.x; acc[1][1] += a1 * w0.y; acc[1][2] += a1 * w0.z; acc[1][3] += a1 * w0.w;
      acc[1][4] += a1 * w1.x; acc[1][5] += a1 * w1.y; acc[1][6] += a1 * w1.z; acc[1][7] += a1 * w1.w;
      acc[2][0] += a2 * w0.x; acc[2][1] += a2 * w0.y; acc[2][2] += a2 * w0.z; acc[2][3] += a2 * w0.w;
      acc[2][4] += a2 * w1.x; acc[2][5] += a2 * w1.y; acc[2][6] += a2 * w1.z; acc[2][7] += a2 * w1.w;
      acc[3][0] += a3 * w0.x; acc[3][1] += a3 * w0.y; acc[3][2] += a3 * w0.z; acc[3][3] += a3 * w0.w;
      acc[3][4] += a3 * w1.x; acc[3][5] += a3 * w1.y; acc[3][6] += a3 * w1.z; acc[3][7] += a3 * w1.w;
    }
    float4 b0 = *(const float4*)&b_ih[col0];
    float4 b1 = *(const float4*)&b_ih[col0 + 4];
#pragma unroll
    for (int a = 0; a < 4; ++a) {
      int row = row0 + ty * 4 + a;
      float4 o0, o1;
      o0.x = acc[a][0] + b0.x; o0.y = acc[a][1] + b0.y; o0.z = acc[a][2] + b0.z; o0.w = acc[a][3] + b0.w;
      o1.x = acc[a][4] + b1.x; o1.y = acc[a][5] + b1.y; o1.z = acc[a][6] + b1.z; o1.w = acc[a][7] + b1.w;
      *(float4*)&xp[(size_t)row * G3_ + col0] = o0;
      *(float4*)&xp[(size_t)row * G3_ + col0 + 4] = o1;
    }
  }
}

// ---------- GRU recurrence: 64 blocks (1 batch elem each), W_hh in VGPRs ----------
__global__ __launch_bounds__(256, 1) void gru_kernel(
    const float* __restrict__ xp, const unsigned* __restrict__ Wreg,
    const float* __restrict__ b_hh, float* __restrict__ enc) {
  int u = threadIdx.x;                   // hidden unit owned by this thread
  int b = blockIdx.x;
  __shared__ alignas(16) unsigned short hsb[256];   // h state, bf16
  unsigned w[384];                       // 3 gate rows x 128 bf16-pairs, in VGPRs
#pragma unroll
  for (int j4 = 0; j4 < 96; ++j4) {
    uint4 q = ((const uint4*)Wreg)[j4 * 256 + u];   // coalesced dwordx4
    w[j4 * 4 + 0] = q.x; w[j4 * 4 + 1] = q.y;
    w[j4 * 4 + 2] = q.z; w[j4 * 4 + 3] = q.w;
  }
  float bhr = b_hh[u], bhz = b_hh[256 + u], bhn = b_hh[512 + u];
  hsb[u] = 0;                            // h0 = 0
  float hold = 0.f;
  const float* xpb = xp + (size_t)b * T_ * G3_;
  float* encb = enc + (size_t)b * T_ * H_;
  __syncthreads();
  for (int t = 0; t < T_; ++t) {
    float ar = xpb[t * G3_ + u];
    float az = xpb[t * G3_ + 256 + u];
    float an = xpb[t * G3_ + 512 + u];
    float hr0 = 0.f, hr1 = 0.f, hz0 = 0.f, hz1 = 0.f, hn0 = 0.f, hn1 = 0.f;
    const uint4* h4 = (const uint4*)hsb;
#pragma unroll
    for (int q = 0; q < 32; ++q) {
      uint4 hq = h4[q];                  // uniform addr -> LDS broadcast
      dot2bf(hr0, hq.x, w[q * 4 + 0]);
      dot2bf(hz0, hq.x, w[128 + q * 4 + 0]);
      dot2bf(hn0, hq.x, w[256 + q * 4 + 0]);
      dot2bf(hr1, hq.y, w[q * 4 + 1]);
      dot2bf(hz1, hq.y, w[128 + q * 4 + 1]);
      dot2bf(hn1, hq.y, w[256 + q * 4 + 1]);
      dot2bf(hr0, hq.z, w[q * 4 + 2]);
      dot2bf(hz0, hq.z, w[128 + q * 4 + 2]);
      dot2bf(hn0, hq.z, w[256 + q * 4 + 2]);
      dot2bf(hr1, hq.w, w[q * 4 + 3]);
      dot2bf(hz1, hq.w, w[128 + q * 4 + 3]);
      dot2bf(hn1, hq.w, w[256 + q * 4 + 3]);
    }
    float hr = bhr + hr0 + hr1;
    float hz = bhz + hz0 + hz1;
    float hn = bhn + hn0 + hn1;
    float r = 1.f / (1.f + __expf(-(ar + hr)));
    float z = 1.f / (1.f + __expf(-(az + hz)));
    float a = an + r * hn;
    a = fminf(15.f, fmaxf(-15.f, a));
    float e = __expf(2.f * a);
    float n = (e - 1.f) / (e + 1.f);     // tanh
    float hnew = (1.f - z) * n + z * hold;
    hold = hnew;                         // exact fp32 state stays in-register
    encb[t * H_ + u] = hnew;
    __syncthreads();                     // all dot-reads of old h done
    hsb[u] = f2bf(hnew);
    __syncthreads();                     // h visible for next step
  }
}

// ---------- anchor[b][d] = enc[b,0,:] . W_mx[d] + b_mx[d],  d<2 ----------
__global__ void anchor_kernel(const float* __restrict__ enc,
                              const float* __restrict__ W_mx,
                              const float* __restrict__ b_mx,
                              float* __restrict__ anchor) {
  int tid = threadIdx.x;
  if (tid < 128) {
    int b = tid >> 1, d = tid & 1;
    const float* e = enc + (size_t)b * T_ * H_;    // t = 0 row
    float acc = b_mx[d];
    for (int k = 0; k < 256; ++k) acc += e[k] * W_mx[d * 256 + k];
    anchor[b * 2 + d] = acc;
  }
}

// ---------- heads: enc[16384,256] x WheadT[256,96] + scatter prep ----------
__global__ __launch_bounds__(256) void heads_kernel(
    const float* __restrict__ enc, const float* __restrict__ WheadT,
    const float* __restrict__ b_mz, const float* __restrict__ b_mx,
    const float* __restrict__ b_pz, const float* __restrict__ b_cx,
    const float* __restrict__ anchor,
    float* __restrict__ out_meanz, float* __restrict__ out_meanx,
    float* __restrict__ out_covx, float* __restrict__ stage) {
  __shared__ float el[8 * 256];
  int tid = threadIdx.x;
  int row0 = blockIdx.x * 8;
  const float4* e4 = (const float4*)(enc + (size_t)row0 * 256);
  float4* el4 = (float4*)el;
  el4[tid] = e4[tid];
  el4[256 + tid] = e4[256 + tid];
  __syncthreads();
#pragma unroll
  for (int i = 0; i < 3; ++i) {
    int idx = i * 256 + tid;             // 768 = 8 rows x 96 cols
    int rl = idx / 96, c = idx % 96;
    const float* er = &el[rl * 256];
    float acc = 0.f;
#pragma unroll 4
    for (int k = 0; k < 256; ++k) acc += er[k] * WheadT[k * 96 + c];
    int row = row0 + rl;
    int bb = row >> 8;
    if (c < 8) {
      out_meanz[(size_t)row * 8 + c] = acc + b_mz[c];
    } else if (c < 16) {
      int d = c - 8;
      float v = acc + b_mx[d];
      if (d < 2) v -= anchor[bb * 2 + d];
      out_meanx[(size_t)row * 8 + d] = v;
    } else if (c < 32) {
      int d = c - 16;
      float v = acc + b_pz[d];
      if (d < 8)                          // diag: softplus (stable)
        v = (v > 0.f) ? (v + log1pf(__expf(-v))) : log1pf(__expf(v));
      stage[(size_t)row * 16 + d] = v;
    } else {
      int d = c - 32;
      out_covx[(size_t)row * 64 + d] = acc + b_cx[d];
    }
  }
}

// ---------- zero the 134 MB chol region ----------
__global__ __launch_bounds__(256) void zero_chol(float4* __restrict__ p, int n4) {
  int i = blockIdx.x * 256 + threadIdx.x;
  int stride = gridDim.x * 256;
  float4 z = {0.f, 0.f, 0.f, 0.f};
  for (; i < n4; i += stride) p[i] = z;
}

// ---------- scatter diag/off into chol ----------
__global__ __launch_bounds__(256) void scatter_chol(
    const float* __restrict__ stage, float* __restrict__ chol) {
  int i = blockIdx.x * 256 + threadIdx.x;   // 262144 = 16384 rows x 16
  int row = i >> 4, d = i & 15;
  int bb = row >> 8, tt = row & 255;
  float v = stage[i];
  if (d < 8) {
    chol[(((size_t)d * 64 + bb) * 256 + tt) * 256 + tt] = v;
  } else if (tt < 255) {
    chol[(((size_t)(d - 8) * 64 + bb) * 256 + tt) * 256 + tt + 1] = v;
  }
}

extern "C" void kernel_launch(void* const* d_in, const int* in_sizes, int n_in,
                              void* d_out, int out_size, void* d_ws, size_t ws_size,
                              hipStream_t stream) {
  const float* y    = (const float*)d_in[0];
  const float* W_ih = (const float*)d_in[1];
  const float* W_hh = (const float*)d_in[2];
  const float* b_ih = (const float*)d_in[3];
  const float* b_hh = (const float*)d_in[4];
  const float* W_mz = (const float*)d_in[5];
  const float* b_mz = (const float*)d_in[6];
  const float* W_mx = (const float*)d_in[7];
  const float* b_mx = (const float*)d_in[8];
  const float* W_pz = (const float*)d_in[9];
  const float* b_pz = (const float*)d_in[10];
  const float* W_cx = (const float*)d_in[11];
  const float* b_cx = (const float*)d_in[12];

  float* out    = (float*)d_out;
  float* mean_z = out;                    // [64,256,8]
  float* chol   = out + 131072;           // [8,64,256,256] = 33554432
  float* mean_x = out + 33685504;         // [16384,8]
  float* cov_x  = out + 33816576;         // [16384,8,8]

  float* ws      = (float*)d_ws;          // ~1.9 MB used
  float* WT_ih   = ws;                    // 98304
  float* WheadT  = ws + 98304;            // 24576
  unsigned* Wreg = (unsigned*)(ws + 122880); // 98304
  float* anchor  = ws + 221184;           // 128
  float* stage   = ws + 221312;           // 262144

  // large scratch lives inside the chol output region (zeroed afterwards)
  float* xp  = chol;                      // 12582912 floats
  float* enc = chol + 12582912;           // 4194304 floats

  prep_kernel<<<864, 256, 0, stream>>>(W_ih, W_hh, W_mz, W_mx, W_pz, W_cx,
                                       WT_ih, WheadT, Wreg);
  xproj_kernel<<<256, 256, 0, stream>>>(y, WT_ih, b_ih, xp);
  gru_kernel<<<64, 256, 0, stream>>>(xp, Wreg, b_hh, enc);
  anchor_kernel<<<1, 128, 0, stream>>>(enc, W_mx, b_mx, anchor);
  heads_kernel<<<2048, 256, 0, stream>>>(enc, WheadT, b_mz, b_mx, b_pz, b_cx,
                                         anchor, mean_z, mean_x, cov_x, stage);
  zero_chol<<<8192, 256, 0, stream>>>((float4*)chol, 8388608);
  scatter_chol<<<1024, 256, 0, stream>>>(stage, chol);
}

// Round 6
// 859.326 us; speedup vs baseline: 1.2148x; 1.2148x over previous
//
#include <hip/hip_runtime.h>
#include <cstdint>
#include <cstddef>

#define B_   64
#define T_   256
#define DIN_ 128
#define H_   256
#define G3_  768   // 3*H

// ---------- helpers ----------
__device__ __forceinline__ unsigned short f2bf(float f) {
  unsigned u = __float_as_uint(f);
  unsigned r = u + 0x7fffu + ((u >> 16) & 1u);   // RNE
  return (unsigned short)(r >> 16);
}

// acc += dot(v2bf16(a), v2bf16(b)) in fp32
__device__ __forceinline__ void dot2bf(float& acc, unsigned a, unsigned b) {
  asm("v_dot2_f32_bf16 %0, %1, %2, %0" : "+v"(acc) : "v"(a), "v"(b));
}

// ---------- prep: transpose W_ih, concat head weights, repack W_hh to bf16 ----------
// Wreg layout for k-split gru: thread t=(og*4+ks), j in [0,32), c in [0,4):
//   a = j>>3 (output sub-index), p = j&7 (pair-block)
//   Wreg[(j*768+t)*4+c] = bf16pair(W_hh[4*og+a][64*ks+8*p+2*c], ...+1)
__global__ __launch_bounds__(256) void prep_kernel(
    const float* __restrict__ W_ih, const float* __restrict__ W_hh,
    const float* __restrict__ W_mz, const float* __restrict__ W_mx,
    const float* __restrict__ W_pz, const float* __restrict__ W_cx,
    float* __restrict__ WT_ih, float* __restrict__ WheadT,
    unsigned* __restrict__ Wreg) {
  int i = blockIdx.x * 256 + threadIdx.x;
  if (i < 98304) {                       // WT_ih[k*768+g] = W_ih[g*128+k]
    int k = i / 768, g = i % 768;
    WT_ih[i] = W_ih[g * 128 + k];
  } else if (i < 98304 + 24576) {        // WheadT[k*96+c]
    int j = i - 98304;
    int k = j / 96, c = j % 96;
    float v;
    if (c < 8)       v = W_mz[c * 256 + k];
    else if (c < 16) v = W_mx[(c - 8) * 256 + k];
    else if (c < 32) v = W_pz[(c - 16) * 256 + k];
    else             v = W_cx[(c - 32) * 256 + k];
    WheadT[j] = v;
  } else {                               // W_hh bf16-pair repack (k-split layout)
    int m = i - 122880;                  // 0..98303, m = (j*768+t)*4+c
    int c = m & 3, n = m >> 2;
    int j = n / 768, t = n % 768;
    int og = t >> 2, ks = t & 3, a = j >> 3, p = j & 7;
    int row = 4 * og + a;
    int k0 = 64 * ks + 8 * p + 2 * c;
    unsigned short lo = f2bf(W_hh[row * 256 + k0]);
    unsigned short hi = f2bf(W_hh[row * 256 + k0 + 1]);
    Wreg[m] = ((unsigned)hi << 16) | (unsigned)lo;
  }
}

// ---------- x_proj = y @ W_ih^T + b_ih : [16384,128]x[128,768] fp32 ----------
__global__ __launch_bounds__(256) void xproj_kernel(
    const float* __restrict__ y, const float* __restrict__ WT_ih,
    const float* __restrict__ b_ih, float* __restrict__ xp) {
  __shared__ float ylds[32][132];
  int tid = threadIdx.x;
  int row0 = blockIdx.x * 32;
  const float4* y4 = (const float4*)(y + (size_t)row0 * DIN_);
#pragma unroll
  for (int i = 0; i < 4; ++i) {
    int idx = i * 256 + tid;             // 1024 float4 = 32x128
    float4 v = y4[idx];
    int r = idx >> 5, c4 = (idx & 31) * 4;
    ylds[r][c4 + 0] = v.x; ylds[r][c4 + 1] = v.y;
    ylds[r][c4 + 2] = v.z; ylds[r][c4 + 3] = v.w;
  }
  __syncthreads();
  int tx = tid & 15, ty = tid >> 4;      // thread: 2 rows x 8 cols
  for (int c = 0; c < 6; ++c) {
    int col0 = c * 128 + tx * 8;
    float acc[2][8];
#pragma unroll
    for (int a = 0; a < 2; ++a)
#pragma unroll
      for (int b = 0; b < 8; ++b) acc[a][b] = 0.f;
#pragma unroll 4
    for (int k = 0; k < 128; ++k) {
      float4 w0 = *(const float4*)&WT_ih[k * 768 + col0];
      float4 w1 = *(const float4*)&WT_ih[k * 768 + col0 + 4];
      float a0 = ylds[ty * 2 + 0][k], a1 = ylds[ty * 2 + 1][k];
      acc[0][0] += a0 * w0.x; acc[0][1] += a0 * w0.y; acc[0][2] += a0 * w0.z; acc[0][3] += a0 * w0.w;
      acc[0][4] += a0 * w1.x; acc[0][5] += a0 * w1.y; acc[0][6] += a0 * w1.z; acc[0][7] += a0 * w1.w;
      acc[1][0] += a1 * w0.x; acc[1][1] += a1 * w0.y; acc[1][2] += a1 * w0.z; acc[1][3] += a1 * w0.w;
      acc[1][4] += a1 * w1.x; acc[1][5] += a1 * w1.y; acc[1][6] += a1 * w1.z; acc[1][7] += a1 * w1.w;
    }
    float4 b0 = *(const float4*)&b_ih[col0];
    float4 b1 = *(const float4*)&b_ih[col0 + 4];
#pragma unroll
    for (int a = 0; a < 2; ++a) {
      int row = row0 + ty * 2 + a;
      float4 o0, o1;
      o0.x = acc[a][0] + b0.x; o0.y = acc[a][1] + b0.y; o0.z = acc[a][2] + b0.z; o0.w = acc[a][3] + b0.w;
      o1.x = acc[a][4] + b1.x; o1.y = acc[a][5] + b1.y; o1.z = acc[a][6] + b1.z; o1.w = acc[a][7] + b1.w;
      *(float4*)&xp[(size_t)row * G3_ + col0] = o0;
      *(float4*)&xp[(size_t)row * G3_ + col0 + 4] = o1;
    }
  }
}

// ---------- GRU recurrence: 64 blocks x 768 threads ----------
// Hidden state kept as DOUBLE-bf16 (hi+lo) -> ~fp32 precision.
// hsb layout (uint4 units): hi = slots [0,32), lo = slots [32,64).
// Thread (og,ks) computes outputs 4*og..4*og+3 over k-slice [64*ks,64*ks+64)
// against hi then lo; partials reduced via LDS in deterministic order.
__global__ __launch_bounds__(768, 3) void gru_kernel(
    const float* __restrict__ xp, const unsigned* __restrict__ Wreg,
    const float* __restrict__ b_hh, float* __restrict__ enc) {
  int tid = threadIdx.x;
  int u = tid & 255, g = tid >> 8;
  int og = tid >> 2, ks = tid & 3;
  int b = blockIdx.x;
  __shared__ alignas(16) unsigned short hsb[512];   // h: hi[0..255], lo[256..511]
  __shared__ alignas(16) float part[3088];          // 4 slices x 772 (pad 4)
  __shared__ float rzl[512];                        // r,z gate values
  unsigned w[128];
  const uint4* W4 = (const uint4*)Wreg;
#pragma unroll
  for (int j = 0; j < 32; ++j) {
    uint4 q = W4[j * 768 + tid];          // coalesced dwordx4
    w[4 * j + 0] = q.x; w[4 * j + 1] = q.y;
    w[4 * j + 2] = q.z; w[4 * j + 3] = q.w;
  }
  float bh = b_hh[tid];                   // bias for output o = tid
  if (g == 0) { hsb[u] = 0; hsb[256 + u] = 0; }   // h0 = 0
  float hold = 0.f;                       // fp32 state (g==2 threads)
  const float* xpb = xp + (size_t)b * (T_ * G3_);
  float* encb = enc + (size_t)b * (T_ * H_);
  float xv = xpb[tid];                    // prefetch t=0
  __syncthreads();
  for (int t = 0; t < T_; ++t) {
    float p0 = 0.f, p1 = 0.f, p2 = 0.f, p3 = 0.f;
    const uint4* hhi = ((const uint4*)hsb) + (ks << 3);
    const uint4* hlo = hhi + 32;          // lo region starts at uint4 slot 32
#pragma unroll
    for (int r = 0; r < 8; ++r) {
      uint4 hq = hhi[r];
      dot2bf(p0, hq.x, w[(r << 2) + 0]);
      dot2bf(p0, hq.y, w[(r << 2) + 1]);
      dot2bf(p0, hq.z, w[(r << 2) + 2]);
      dot2bf(p0, hq.w, w[(r << 2) + 3]);
      dot2bf(p1, hq.x, w[32 + (r << 2) + 0]);
      dot2bf(p1, hq.y, w[32 + (r << 2) + 1]);
      dot2bf(p1, hq.z, w[32 + (r << 2) + 2]);
      dot2bf(p1, hq.w, w[32 + (r << 2) + 3]);
      dot2bf(p2, hq.x, w[64 + (r << 2) + 0]);
      dot2bf(p2, hq.y, w[64 + (r << 2) + 1]);
      dot2bf(p2, hq.z, w[64 + (r << 2) + 2]);
      dot2bf(p2, hq.w, w[64 + (r << 2) + 3]);
      dot2bf(p3, hq.x, w[96 + (r << 2) + 0]);
      dot2bf(p3, hq.y, w[96 + (r << 2) + 1]);
      dot2bf(p3, hq.z, w[96 + (r << 2) + 2]);
      dot2bf(p3, hq.w, w[96 + (r << 2) + 3]);
    }
#pragma unroll
    for (int r = 0; r < 8; ++r) {
      uint4 hq = hlo[r];
      dot2bf(p0, hq.x, w[(r << 2) + 0]);
      dot2bf(p0, hq.y, w[(r << 2) + 1]);
      dot2bf(p0, hq.z, w[(r << 2) + 2]);
      dot2bf(p0, hq.w, w[(r << 2) + 3]);
      dot2bf(p1, hq.x, w[32 + (r << 2) + 0]);
      dot2bf(p1, hq.y, w[32 + (r << 2) + 1]);
      dot2bf(p1, hq.z, w[32 + (r << 2) + 2]);
      dot2bf(p1, hq.w, w[32 + (r << 2) + 3]);
      dot2bf(p2, hq.x, w[64 + (r << 2) + 0]);
      dot2bf(p2, hq.y, w[64 + (r << 2) + 1]);
      dot2bf(p2, hq.z, w[64 + (r << 2) + 2]);
      dot2bf(p2, hq.w, w[64 + (r << 2) + 3]);
      dot2bf(p3, hq.x, w[96 + (r << 2) + 0]);
      dot2bf(p3, hq.y, w[96 + (r << 2) + 1]);
      dot2bf(p3, hq.z, w[96 + (r << 2) + 2]);
      dot2bf(p3, hq.w, w[96 + (r << 2) + 3]);
    }
    float4 pv;
    pv.x = p0; pv.y = p1; pv.z = p2; pv.w = p3;
    *(float4*)&part[ks * 772 + (og << 2)] = pv;
    __syncthreads();                      // partials visible; h reads done
    float pre = bh + ((part[tid] + part[772 + tid]) +
                      (part[1544 + tid] + part[2316 + tid]));
    float xnext = xpb[(t + 1) * G3_ + tid];     // prefetch (stays in alloc)
    if (g == 0)      rzl[u]       = 1.f / (1.f + __expf(-(xv + pre)));
    else if (g == 1) rzl[256 + u] = 1.f / (1.f + __expf(-(xv + pre)));
    __syncthreads();                      // r,z visible; part reads done
    if (g == 2) {
      float r_ = rzl[u], z = rzl[256 + u];
      float a = xv + r_ * pre;            // xn + r*(hn_dot + bhn)
      a = fminf(15.f, fmaxf(-15.f, a));
      float e = __expf(2.f * a);
      float n = (e - 1.f) / (e + 1.f);    // tanh
      float hnew = (1.f - z) * n + z * hold;
      hold = hnew;
      encb[t * H_ + u] = hnew;
      unsigned short h16 = f2bf(hnew);
      float hif = __uint_as_float(((unsigned)h16) << 16);
      hsb[u] = h16;                       // hi
      hsb[256 + u] = f2bf(hnew - hif);    // lo (residual)
    }
    __syncthreads();                      // new h visible
    xv = xnext;
  }
}

// ---------- anchor[b][d] = enc[b,0,:] . W_mx[d] + b_mx[d],  d<2 ----------
__global__ void anchor_kernel(const float* __restrict__ enc,
                              const float* __restrict__ W_mx,
                              const float* __restrict__ b_mx,
                              float* __restrict__ anchor) {
  int tid = threadIdx.x;
  if (tid < 128) {
    int b = tid >> 1, d = tid & 1;
    const float* e = enc + (size_t)b * T_ * H_;    // t = 0 row
    float acc = b_mx[d];
    for (int k = 0; k < 256; ++k) acc += e[k] * W_mx[d * 256 + k];
    anchor[b * 2 + d] = acc;
  }
}

// ---------- heads: enc[16384,256] x WheadT[256,96] ----------
__global__ __launch_bounds__(256) void heads_kernel(
    const float* __restrict__ enc, const float* __restrict__ WheadT,
    const float* __restrict__ b_mz, const float* __restrict__ b_mx,
    const float* __restrict__ b_pz, const float* __restrict__ b_cx,
    const float* __restrict__ anchor,
    float* __restrict__ out_meanz, float* __restrict__ out_meanx,
    float* __restrict__ out_covx, float* __restrict__ stage) {
  __shared__ float el[8 * 256];
  int tid = threadIdx.x;
  int row0 = blockIdx.x * 8;
  const float4* e4 = (const float4*)(enc + (size_t)row0 * 256);
  float4* el4 = (float4*)el;
  el4[tid] = e4[tid];
  el4[256 + tid] = e4[256 + tid];
  __syncthreads();
#pragma unroll
  for (int i = 0; i < 3; ++i) {
    int idx = i * 256 + tid;             // 768 = 8 rows x 96 cols
    int rl = idx / 96, c = idx % 96;
    const float* er = &el[rl * 256];
    float acc = 0.f;
#pragma unroll 4
    for (int k = 0; k < 256; ++k) acc += er[k] * WheadT[k * 96 + c];
    int row = row0 + rl;
    int bb = row >> 8;
    if (c < 8) {
      out_meanz[(size_t)row * 8 + c] = acc + b_mz[c];
    } else if (c < 16) {
      int d = c - 8;
      float v = acc + b_mx[d];
      if (d < 2) v -= anchor[bb * 2 + d];
      out_meanx[(size_t)row * 8 + d] = v;
    } else if (c < 32) {
      int d = c - 16;
      float v = acc + b_pz[d];
      if (d < 8)                          // diag: softplus (stable)
        v = (v > 0.f) ? (v + log1pf(__expf(-v))) : log1pf(__expf(v));
      stage[(size_t)row * 16 + d] = v;
    } else {
      int d = c - 32;
      out_covx[(size_t)row * 64 + d] = acc + b_cx[d];
    }
  }
}

// ---------- fused zero + banded scatter: write chol in one pass ----------
__global__ __launch_bounds__(256) void chol_kernel(
    const float* __restrict__ stage, float4* __restrict__ chol) {
  int i = blockIdx.x * 256 + threadIdx.x;
  int stride = gridDim.x * 256;
  for (; i < 8388608; i += stride) {
    int d = i >> 20;                    // latent dim 0..7
    int bt = (i >> 6) & 16383;          // b*256 + t
    int t = bt & 255;
    int lane = i & 63;                  // float4 index within row
    float vd = 0.f, vo = 0.f;
    if ((t >> 2) == lane)        vd = stage[bt * 16 + d];       // diag col t
    if (((t + 1) >> 2) == lane)  vo = stage[bt * 16 + 8 + d];   // off col t+1
    int te = t & 3, oe = (t + 1) & 3;
    float4 v;
    v.x = (te == 0 ? vd : 0.f) + (oe == 0 ? vo : 0.f);
    v.y = (te == 1 ? vd : 0.f) + (oe == 1 ? vo : 0.f);
    v.z = (te == 2 ? vd : 0.f) + (oe == 2 ? vo : 0.f);
    v.w = (te == 3 ? vd : 0.f) + (oe == 3 ? vo : 0.f);
    chol[i] = v;
  }
}

extern "C" void kernel_launch(void* const* d_in, const int* in_sizes, int n_in,
                              void* d_out, int out_size, void* d_ws, size_t ws_size,
                              hipStream_t stream) {
  const float* y    = (const float*)d_in[0];
  const float* W_ih = (const float*)d_in[1];
  const float* W_hh = (const float*)d_in[2];
  const float* b_ih = (const float*)d_in[3];
  const float* b_hh = (const float*)d_in[4];
  const float* W_mz = (const float*)d_in[5];
  const float* b_mz = (const float*)d_in[6];
  const float* W_mx = (const float*)d_in[7];
  const float* b_mx = (const float*)d_in[8];
  const float* W_pz = (const float*)d_in[9];
  const float* b_pz = (const float*)d_in[10];
  const float* W_cx = (const float*)d_in[11];
  const float* b_cx = (const float*)d_in[12];

  float* out    = (float*)d_out;
  float* mean_z = out;                    // [64,256,8]
  float* chol   = out + 131072;           // [8,64,256,256]
  float* mean_x = out + 33685504;         // [16384,8]
  float* cov_x  = out + 33816576;         // [16384,8,8]

  float* ws      = (float*)d_ws;
  float* WT_ih   = ws;                    // 98304
  float* WheadT  = ws + 98304;            // 24576
  unsigned* Wreg = (unsigned*)(ws + 122880); // 98304
  float* anchor  = ws + 221184;           // 128
  float* stage   = ws + 221312;           // 262144

  // large scratch inside the chol output region (overwritten by chol_kernel)
  float* xp  = chol;                      // 12582912 floats
  float* enc = chol + 12582912;           // 4194304 floats

  prep_kernel<<<864, 256, 0, stream>>>(W_ih, W_hh, W_mz, W_mx, W_pz, W_cx,
                                       WT_ih, WheadT, Wreg);
  xproj_kernel<<<512, 256, 0, stream>>>(y, WT_ih, b_ih, xp);
  gru_kernel<<<64, 768, 0, stream>>>(xp, Wreg, b_hh, enc);
  anchor_kernel<<<1, 128, 0, stream>>>(enc, W_mx, b_mx, anchor);
  heads_kernel<<<2048, 256, 0, stream>>>(enc, WheadT, b_mz, b_mx, b_pz, b_cx,
                                         anchor, mean_z, mean_x, cov_x, stage);
  chol_kernel<<<8192, 256, 0, stream>>>(stage, (float4*)chol);
}

// Round 7
// 657.727 us; speedup vs baseline: 1.5872x; 1.3065x over previous
//
#include <hip/hip_runtime.h>
#include <cstdint>
#include <cstddef>

#define B_   64
#define T_   256
#define DIN_ 128
#define H_   256
#define G3_  768   // 3*H

// ---------- helpers ----------
__device__ __forceinline__ unsigned short f2h(float f) {
  _Float16 h = (_Float16)f;              // v_cvt_f16_f32 (RNE)
  return __builtin_bit_cast(unsigned short, h);
}

// acc += dot(v2f16(a), v2f16(b)) in fp32
__device__ __forceinline__ void dot2f(float& acc, unsigned a, unsigned b) {
  asm("v_dot2_f32_f16 %0, %1, %2, %0" : "+v"(acc) : "v"(a), "v"(b));
}

// ---------- prep: transpose W_ih, concat head weights, repack W_hh to fp16 ----------
// Wreg layout for k-split gru (wave-uniform ks):
//   gru thread t: og = (t&63)+64*(t>>8) in [0,192), ks = (t>>6)&3
//   j in [0,32): a = j>>3 (output 4*og+a), p = j&7; c in [0,4)
//   Wreg[(j*768+t)*4+c] = f16pair(W_hh[4*og+a][64*ks+8*p+2*c], ...+1)
__global__ __launch_bounds__(256) void prep_kernel(
    const float* __restrict__ W_ih, const float* __restrict__ W_hh,
    const float* __restrict__ W_mz, const float* __restrict__ W_mx,
    const float* __restrict__ W_pz, const float* __restrict__ W_cx,
    float* __restrict__ WT_ih, float* __restrict__ WheadT,
    unsigned* __restrict__ Wreg) {
  int i = blockIdx.x * 256 + threadIdx.x;
  if (i < 98304) {                       // WT_ih[k*768+g] = W_ih[g*128+k]
    int k = i / 768, g = i % 768;
    WT_ih[i] = W_ih[g * 128 + k];
  } else if (i < 98304 + 24576) {        // WheadT[k*96+c]
    int j = i - 98304;
    int k = j / 96, c = j % 96;
    float v;
    if (c < 8)       v = W_mz[c * 256 + k];
    else if (c < 16) v = W_mx[(c - 8) * 256 + k];
    else if (c < 32) v = W_pz[(c - 16) * 256 + k];
    else             v = W_cx[(c - 32) * 256 + k];
    WheadT[j] = v;
  } else {                               // W_hh fp16-pair repack (k-split layout)
    int m = i - 122880;                  // 0..98303, m = (j*768+t)*4+c
    int c = m & 3, n = m >> 2;
    int j = n / 768, t = n % 768;
    int og = (t & 63) + ((t >> 8) << 6);
    int ks = (t >> 6) & 3;
    int a = j >> 3, p = j & 7;
    int row = 4 * og + a;
    int k0 = 64 * ks + 8 * p + 2 * c;
    unsigned short lo = f2h(W_hh[row * 256 + k0]);
    unsigned short hi = f2h(W_hh[row * 256 + k0 + 1]);
    Wreg[m] = ((unsigned)hi << 16) | (unsigned)lo;
  }
}

// ---------- x_proj = y @ W_ih^T + b_ih : [16384,128]x[128,768] fp32 ----------
__global__ __launch_bounds__(256) void xproj_kernel(
    const float* __restrict__ y, const float* __restrict__ WT_ih,
    const float* __restrict__ b_ih, float* __restrict__ xp) {
  __shared__ float ylds[32][132];
  int tid = threadIdx.x;
  int row0 = blockIdx.x * 32;
  const float4* y4 = (const float4*)(y + (size_t)row0 * DIN_);
#pragma unroll
  for (int i = 0; i < 4; ++i) {
    int idx = i * 256 + tid;             // 1024 float4 = 32x128
    float4 v = y4[idx];
    int r = idx >> 5, c4 = (idx & 31) * 4;
    ylds[r][c4 + 0] = v.x; ylds[r][c4 + 1] = v.y;
    ylds[r][c4 + 2] = v.z; ylds[r][c4 + 3] = v.w;
  }
  __syncthreads();
  int tx = tid & 15, ty = tid >> 4;      // thread: 2 rows x 8 cols
  for (int c = 0; c < 6; ++c) {
    int col0 = c * 128 + tx * 8;
    float acc[2][8];
#pragma unroll
    for (int a = 0; a < 2; ++a)
#pragma unroll
      for (int b = 0; b < 8; ++b) acc[a][b] = 0.f;
#pragma unroll 4
    for (int k = 0; k < 128; ++k) {
      float4 w0 = *(const float4*)&WT_ih[k * 768 + col0];
      float4 w1 = *(const float4*)&WT_ih[k * 768 + col0 + 4];
      float a0 = ylds[ty * 2 + 0][k], a1 = ylds[ty * 2 + 1][k];
      acc[0][0] += a0 * w0.x; acc[0][1] += a0 * w0.y; acc[0][2] += a0 * w0.z; acc[0][3] += a0 * w0.w;
      acc[0][4] += a0 * w1.x; acc[0][5] += a0 * w1.y; acc[0][6] += a0 * w1.z; acc[0][7] += a0 * w1.w;
      acc[1][0] += a1 * w0.x; acc[1][1] += a1 * w0.y; acc[1][2] += a1 * w0.z; acc[1][3] += a1 * w0.w;
      acc[1][4] += a1 * w1.x; acc[1][5] += a1 * w1.y; acc[1][6] += a1 * w1.z; acc[1][7] += a1 * w1.w;
    }
    float4 b0 = *(const float4*)&b_ih[col0];
    float4 b1 = *(const float4*)&b_ih[col0 + 4];
#pragma unroll
    for (int a = 0; a < 2; ++a) {
      int row = row0 + ty * 2 + a;
      float4 o0, o1;
      o0.x = acc[a][0] + b0.x; o0.y = acc[a][1] + b0.y; o0.z = acc[a][2] + b0.z; o0.w = acc[a][3] + b0.w;
      o1.x = acc[a][4] + b1.x; o1.y = acc[a][5] + b1.y; o1.z = acc[a][6] + b1.z; o1.w = acc[a][7] + b1.w;
      *(float4*)&xp[(size_t)row * G3_ + col0] = o0;
      *(float4*)&xp[(size_t)row * G3_ + col0 + 4] = o1;
    }
  }
}

// ---------- GRU recurrence: 64 blocks x 768 threads ----------
// Hidden state fp16 (8x less quantization noise than bf16), single dot pass.
// ks = (tid>>6)&3 is wave-uniform -> LDS h reads are pure broadcast (0 conflicts).
// waves_per_eu(3,3) pins occupancy so w[128] stays in VGPRs (no AGPR/scratch).
__global__ __launch_bounds__(768) __attribute__((amdgpu_waves_per_eu(3, 3)))
void gru_kernel(
    const float* __restrict__ xp, const unsigned* __restrict__ Wreg,
    const float* __restrict__ b_hh, float* __restrict__ enc) {
  int tid = threadIdx.x;
  int u = tid & 255, g = tid >> 8;
  int og = (tid & 63) + ((tid >> 8) << 6);   // [0,192)
  int ks = (tid >> 6) & 3;                   // wave-uniform k-slice
  int b = blockIdx.x;
  __shared__ alignas(16) unsigned short hsb[256];   // h state, fp16
  __shared__ alignas(16) float part[3088];          // 4 slices x 772 (pad 4)
  __shared__ float rzl[512];                        // r,z gate values
  unsigned w[128];
  const uint4* W4 = (const uint4*)Wreg;
#pragma unroll
  for (int j = 0; j < 32; ++j) {
    uint4 q = W4[j * 768 + tid];          // coalesced dwordx4
    w[4 * j + 0] = q.x; w[4 * j + 1] = q.y;
    w[4 * j + 2] = q.z; w[4 * j + 3] = q.w;
  }
  float bh = b_hh[tid];                   // bias for output o = tid
  if (g == 0) hsb[u] = 0;                 // h0 = 0 (fp16 zero)
  float hold = 0.f;                       // fp32 state (g==2 threads)
  const float* xpb = xp + (size_t)b * (T_ * G3_);
  float* encb = enc + (size_t)b * (T_ * H_);
  float xv = xpb[tid];                    // prefetch t=0
  __syncthreads();
  for (int t = 0; t < T_; ++t) {
    float p0 = 0.f, p1 = 0.f, p2 = 0.f, p3 = 0.f;
    const uint4* hs = ((const uint4*)hsb) + (ks << 3);   // 8 uint4 = 64 fp16
#pragma unroll
    for (int r = 0; r < 8; ++r) {
      uint4 hq = hs[r];                   // uniform addr -> LDS broadcast
      dot2f(p0, hq.x, w[(r << 2) + 0]);
      dot2f(p0, hq.y, w[(r << 2) + 1]);
      dot2f(p0, hq.z, w[(r << 2) + 2]);
      dot2f(p0, hq.w, w[(r << 2) + 3]);
      dot2f(p1, hq.x, w[32 + (r << 2) + 0]);
      dot2f(p1, hq.y, w[32 + (r << 2) + 1]);
      dot2f(p1, hq.z, w[32 + (r << 2) + 2]);
      dot2f(p1, hq.w, w[32 + (r << 2) + 3]);
      dot2f(p2, hq.x, w[64 + (r << 2) + 0]);
      dot2f(p2, hq.y, w[64 + (r << 2) + 1]);
      dot2f(p2, hq.z, w[64 + (r << 2) + 2]);
      dot2f(p2, hq.w, w[64 + (r << 2) + 3]);
      dot2f(p3, hq.x, w[96 + (r << 2) + 0]);
      dot2f(p3, hq.y, w[96 + (r << 2) + 1]);
      dot2f(p3, hq.z, w[96 + (r << 2) + 2]);
      dot2f(p3, hq.w, w[96 + (r << 2) + 3]);
    }
    float4 pv;
    pv.x = p0; pv.y = p1; pv.z = p2; pv.w = p3;
    *(float4*)&part[ks * 772 + (og << 2)] = pv;   // outputs 4*og..4*og+3
    __syncthreads();                      // partials visible; h reads done
    float pre = bh + ((part[tid] + part[772 + tid]) +
                      (part[1544 + tid] + part[2316 + tid]));
    float xnext = xpb[(t + 1) * G3_ + tid];     // prefetch (stays in alloc)
    if (g == 0)      rzl[u]       = 1.f / (1.f + __expf(-(xv + pre)));
    else if (g == 1) rzl[256 + u] = 1.f / (1.f + __expf(-(xv + pre)));
    __syncthreads();                      // r,z visible; part reads done
    if (g == 2) {
      float r_ = rzl[u], z = rzl[256 + u];
      float a = xv + r_ * pre;            // xn + r*(hn_dot + bhn)
      a = fminf(15.f, fmaxf(-15.f, a));
      float e = __expf(2.f * a);
      float n = (e - 1.f) / (e + 1.f);    // tanh
      float hnew = (1.f - z) * n + z * hold;
      hold = hnew;                        // exact fp32 state in-register
      encb[t * H_ + u] = hnew;
      hsb[u] = f2h(hnew);                 // |h|<=1, fp16 safe
    }
    __syncthreads();                      // new h visible
    xv = xnext;
  }
}

// ---------- anchor[b][d] = enc[b,0,:] . W_mx[d] + b_mx[d],  d<2 ----------
__global__ void anchor_kernel(const float* __restrict__ enc,
                              const float* __restrict__ W_mx,
                              const float* __restrict__ b_mx,
                              float* __restrict__ anchor) {
  int tid = threadIdx.x;
  if (tid < 128) {
    int b = tid >> 1, d = tid & 1;
    const float* e = enc + (size_t)b * T_ * H_;    // t = 0 row
    float acc = b_mx[d];
    for (int k = 0; k < 256; ++k) acc += e[k] * W_mx[d * 256 + k];
    anchor[b * 2 + d] = acc;
  }
}

// ---------- heads: enc[16384,256] x WheadT[256,96] ----------
__global__ __launch_bounds__(256) void heads_kernel(
    const float* __restrict__ enc, const float* __restrict__ WheadT,
    const float* __restrict__ b_mz, const float* __restrict__ b_mx,
    const float* __restrict__ b_pz, const float* __restrict__ b_cx,
    const float* __restrict__ anchor,
    float* __restrict__ out_meanz, float* __restrict__ out_meanx,
    float* __restrict__ out_covx, float* __restrict__ stage) {
  __shared__ float el[8 * 256];
  int tid = threadIdx.x;
  int row0 = blockIdx.x * 8;
  const float4* e4 = (const float4*)(enc + (size_t)row0 * 256);
  float4* el4 = (float4*)el;
  el4[tid] = e4[tid];
  el4[256 + tid] = e4[256 + tid];
  __syncthreads();
#pragma unroll
  for (int i = 0; i < 3; ++i) {
    int idx = i * 256 + tid;             // 768 = 8 rows x 96 cols
    int rl = idx / 96, c = idx % 96;
    const float* er = &el[rl * 256];
    float acc = 0.f;
#pragma unroll 4
    for (int k = 0; k < 256; ++k) acc += er[k] * WheadT[k * 96 + c];
    int row = row0 + rl;
    int bb = row >> 8;
    if (c < 8) {
      out_meanz[(size_t)row * 8 + c] = acc + b_mz[c];
    } else if (c < 16) {
      int d = c - 8;
      float v = acc + b_mx[d];
      if (d < 2) v -= anchor[bb * 2 + d];
      out_meanx[(size_t)row * 8 + d] = v;
    } else if (c < 32) {
      int d = c - 16;
      float v = acc + b_pz[d];
      if (d < 8)                          // diag: softplus (stable)
        v = (v > 0.f) ? (v + log1pf(__expf(-v))) : log1pf(__expf(v));
      stage[(size_t)row * 16 + d] = v;
    } else {
      int d = c - 32;
      out_covx[(size_t)row * 64 + d] = acc + b_cx[d];
    }
  }
}

// ---------- fused zero + banded scatter: write chol in one pass ----------
__global__ __launch_bounds__(256) void chol_kernel(
    const float* __restrict__ stage, float4* __restrict__ chol) {
  int i = blockIdx.x * 256 + threadIdx.x;
  int stride = gridDim.x * 256;
  for (; i < 8388608; i += stride) {
    int d = i >> 20;                    // latent dim 0..7
    int bt = (i >> 6) & 16383;          // b*256 + t
    int t = bt & 255;
    int lane = i & 63;                  // float4 index within row
    float vd = 0.f, vo = 0.f;
    if ((t >> 2) == lane)        vd = stage[bt * 16 + d];       // diag col t
    if (((t + 1) >> 2) == lane)  vo = stage[bt * 16 + 8 + d];   // off col t+1
    int te = t & 3, oe = (t + 1) & 3;
    float4 v;
    v.x = (te == 0 ? vd : 0.f) + (oe == 0 ? vo : 0.f);
    v.y = (te == 1 ? vd : 0.f) + (oe == 1 ? vo : 0.f);
    v.z = (te == 2 ? vd : 0.f) + (oe == 2 ? vo : 0.f);
    v.w = (te == 3 ? vd : 0.f) + (oe == 3 ? vo : 0.f);
    chol[i] = v;
  }
}

extern "C" void kernel_launch(void* const* d_in, const int* in_sizes, int n_in,
                              void* d_out, int out_size, void* d_ws, size_t ws_size,
                              hipStream_t stream) {
  const float* y    = (const float*)d_in[0];
  const float* W_ih = (const float*)d_in[1];
  const float* W_hh = (const float*)d_in[2];
  const float* b_ih = (const float*)d_in[3];
  const float* b_hh = (const float*)d_in[4];
  const float* W_mz = (const float*)d_in[5];
  const float* b_mz = (const float*)d_in[6];
  const float* W_mx = (const float*)d_in[7];
  const float* b_mx = (const float*)d_in[8];
  const float* W_pz = (const float*)d_in[9];
  const float* b_pz = (const float*)d_in[10];
  const float* W_cx = (const float*)d_in[11];
  const float* b_cx = (const float*)d_in[12];

  float* out    = (float*)d_out;
  float* mean_z = out;                    // [64,256,8]
  float* chol   = out + 131072;           // [8,64,256,256]
  float* mean_x = out + 33685504;         // [16384,8]
  float* cov_x  = out + 33816576;         // [16384,8,8]

  float* ws      = (float*)d_ws;
  float* WT_ih   = ws;                    // 98304
  float* WheadT  = ws + 98304;            // 24576
  unsigned* Wreg = (unsigned*)(ws + 122880); // 98304
  float* anchor  = ws + 221184;           // 128
  float* stage   = ws + 221312;           // 262144

  // large scratch inside the chol output region (overwritten by chol_kernel)
  float* xp  = chol;                      // 12582912 floats
  float* enc = chol + 12582912;           // 4194304 floats

  prep_kernel<<<864, 256, 0, stream>>>(W_ih, W_hh, W_mz, W_mx, W_pz, W_cx,
                                       WT_ih, WheadT, Wreg);
  xproj_kernel<<<512, 256, 0, stream>>>(y, WT_ih, b_ih, xp);
  gru_kernel<<<64, 768, 0, stream>>>(xp, Wreg, b_hh, enc);
  anchor_kernel<<<1, 128, 0, stream>>>(enc, W_mx, b_mx, anchor);
  heads_kernel<<<2048, 256, 0, stream>>>(enc, WheadT, b_mz, b_mx, b_pz, b_cx,
                                         anchor, mean_z, mean_x, cov_x, stage);
  chol_kernel<<<8192, 256, 0, stream>>>(stage, (float4*)chol);
}

// Round 8
// 629.024 us; speedup vs baseline: 1.6596x; 1.0456x over previous
//
#include <hip/hip_runtime.h>
#include <cstdint>
#include <cstddef>

#define B_   64
#define T_   256
#define DIN_ 128
#define H_   256
#define G3_  768   // 3*H

// ---------- helpers ----------
__device__ __forceinline__ unsigned short f2h(float f) {
  _Float16 h = (_Float16)f;              // v_cvt_f16_f32 (RNE)
  return __builtin_bit_cast(unsigned short, h);
}

// acc += dot(v2f16(a), v2f16(b)) in fp32
__device__ __forceinline__ void dot2f(float& acc, unsigned a, unsigned b) {
  asm("v_dot2_f32_f16 %0, %1, %2, %0" : "+v"(acc) : "v"(a), "v"(b));
}

// ---------- prep ----------
// Wreg layout for 512-thread gru: thread t: ks = t>>7, og = t&127.
// Thread owns outputs o = a*128+og (a in [0,6)) over k-slice [64*ks, 64*ks+64).
// w[j] (j = a*32 + qp, qp in [0,32) = k-pair): loaded as uint4 j4 = j>>2:
//   Wreg[(j4*512 + t)*4 + (j&3)] = f16pair(W_hh[o][64*ks+2*qp], [..+1])
// WheadT layout: [c][k]  (c in [0,96), k in [0,256))
__global__ __launch_bounds__(256) void prep_kernel(
    const float* __restrict__ W_ih, const float* __restrict__ W_hh,
    const float* __restrict__ W_mz, const float* __restrict__ W_mx,
    const float* __restrict__ W_pz, const float* __restrict__ W_cx,
    float* __restrict__ WT_ih, float* __restrict__ WheadT,
    unsigned* __restrict__ Wreg) {
  int i = blockIdx.x * 256 + threadIdx.x;
  if (i < 98304) {                       // WT_ih[k*768+g] = W_ih[g*128+k]
    int k = i / 768, g = i % 768;
    WT_ih[i] = W_ih[g * 128 + k];
  } else if (i < 98304 + 24576) {        // WheadT[c*256+k]
    int j = i - 98304;
    int c = j >> 8, k = j & 255;
    float v;
    if (c < 8)       v = W_mz[c * 256 + k];
    else if (c < 16) v = W_mx[(c - 8) * 256 + k];
    else if (c < 32) v = W_pz[(c - 16) * 256 + k];
    else             v = W_cx[(c - 32) * 256 + k];
    WheadT[j] = v;
  } else {                               // W_hh fp16-pair repack
    int m = i - 122880;                  // 0..98303
    int c = m & 3, n = m >> 2;
    int t = n & 511, j4 = n >> 9;        // j4 in [0,48)
    int j = 4 * j4 + c;                  // [0,192)
    int a = j >> 5, qp = j & 31;
    int o = a * 128 + (t & 127);
    int k0 = ((t >> 7) << 6) + 2 * qp;
    unsigned short lo = f2h(W_hh[o * 256 + k0]);
    unsigned short hi = f2h(W_hh[o * 256 + k0 + 1]);
    Wreg[m] = ((unsigned)hi << 16) | (unsigned)lo;
  }
}

// ---------- x_proj = y @ W_ih^T + b_ih : [16384,128]x[128,768] fp32 ----------
__global__ __launch_bounds__(256) void xproj_kernel(
    const float* __restrict__ y, const float* __restrict__ WT_ih,
    const float* __restrict__ b_ih, float* __restrict__ xp) {
  __shared__ float ylds[32][132];
  int tid = threadIdx.x;
  int row0 = blockIdx.x * 32;
  const float4* y4 = (const float4*)(y + (size_t)row0 * DIN_);
#pragma unroll
  for (int i = 0; i < 4; ++i) {
    int idx = i * 256 + tid;             // 1024 float4 = 32x128
    float4 v = y4[idx];
    int r = idx >> 5, c4 = (idx & 31) * 4;
    ylds[r][c4 + 0] = v.x; ylds[r][c4 + 1] = v.y;
    ylds[r][c4 + 2] = v.z; ylds[r][c4 + 3] = v.w;
  }
  __syncthreads();
  int tx = tid & 15, ty = tid >> 4;      // thread: 2 rows x 8 cols
  for (int c = 0; c < 6; ++c) {
    int col0 = c * 128 + tx * 8;
    float acc[2][8];
#pragma unroll
    for (int a = 0; a < 2; ++a)
#pragma unroll
      for (int b = 0; b < 8; ++b) acc[a][b] = 0.f;
#pragma unroll 4
    for (int k = 0; k < 128; ++k) {
      float4 w0 = *(const float4*)&WT_ih[k * 768 + col0];
      float4 w1 = *(const float4*)&WT_ih[k * 768 + col0 + 4];
      float a0 = ylds[ty * 2 + 0][k], a1 = ylds[ty * 2 + 1][k];
      acc[0][0] += a0 * w0.x; acc[0][1] += a0 * w0.y; acc[0][2] += a0 * w0.z; acc[0][3] += a0 * w0.w;
      acc[0][4] += a0 * w1.x; acc[0][5] += a0 * w1.y; acc[0][6] += a0 * w1.z; acc[0][7] += a0 * w1.w;
      acc[1][0] += a1 * w0.x; acc[1][1] += a1 * w0.y; acc[1][2] += a1 * w0.z; acc[1][3] += a1 * w0.w;
      acc[1][4] += a1 * w1.x; acc[1][5] += a1 * w1.y; acc[1][6] += a1 * w1.z; acc[1][7] += a1 * w1.w;
    }
    float4 b0 = *(const float4*)&b_ih[col0];
    float4 b1 = *(const float4*)&b_ih[col0 + 4];
#pragma unroll
    for (int a = 0; a < 2; ++a) {
      int row = row0 + ty * 2 + a;
      float4 o0, o1;
      o0.x = acc[a][0] + b0.x; o0.y = acc[a][1] + b0.y; o0.z = acc[a][2] + b0.z; o0.w = acc[a][3] + b0.w;
      o1.x = acc[a][4] + b1.x; o1.y = acc[a][5] + b1.y; o1.z = acc[a][6] + b1.z; o1.w = acc[a][7] + b1.w;
      *(float4*)&xp[(size_t)row * G3_ + col0] = o0;
      *(float4*)&xp[(size_t)row * G3_ + col0 + 4] = o1;
    }
  }
}

// ---------- GRU recurrence: 64 blocks x 512 threads ----------
// 8 waves = 2/SIMD -> 256-reg cap: w[192] stays in VGPRs (no AGPR moves).
// ks = tid>>7 wave-uniform -> LDS h reads are broadcast. 2 barriers/step.
// Threads 0-255 do the full gate math from the part array. xp prefetch dist 2.
__global__ __launch_bounds__(512, 2) void gru_kernel(
    const float* __restrict__ xp, const unsigned* __restrict__ Wreg,
    const float* __restrict__ b_hh, float* __restrict__ enc) {
  int tid = threadIdx.x;
  int ks = tid >> 7;                     // wave-uniform k-slice [64ks,64ks+64)
  int og = tid & 127;                    // outputs a*128+og
  int b = blockIdx.x;
  __shared__ alignas(16) unsigned short hsb[256];   // h state, fp16
  __shared__ alignas(16) float part[3104];          // 4 slices x 776 (pad 8)
  unsigned w[192];
  const uint4* W4 = (const uint4*)Wreg;
#pragma unroll
  for (int j4 = 0; j4 < 48; ++j4) {
    uint4 q = W4[j4 * 512 + tid];        // coalesced dwordx4
    w[4 * j4 + 0] = q.x; w[4 * j4 + 1] = q.y;
    w[4 * j4 + 2] = q.z; w[4 * j4 + 3] = q.w;
  }
  const float* xpb = xp + (size_t)b * (T_ * G3_);
  float* encb = enc + (size_t)b * (T_ * H_);
  float bhr = 0.f, bhz = 0.f, bhn = 0.f, hold = 0.f;
  float xr0 = 0.f, xz0 = 0.f, xn0 = 0.f, xr1 = 0.f, xz1 = 0.f, xn1 = 0.f;
  if (tid < 256) {
    bhr = b_hh[tid]; bhz = b_hh[256 + tid]; bhn = b_hh[512 + tid];
    xr0 = xpb[tid];        xz0 = xpb[256 + tid];        xn0 = xpb[512 + tid];
    xr1 = xpb[768 + tid];  xz1 = xpb[1024 + tid];       xn1 = xpb[1280 + tid];
    hsb[tid] = 0;                        // h0 = 0
  }
  __syncthreads();
  for (int t = 0; t < T_; ++t) {
    float xr2 = 0.f, xz2 = 0.f, xn2 = 0.f;
    if (tid < 256) {                     // prefetch t+2 (overrun lands in scratch)
      int base = (t + 2) * G3_ + tid;
      xr2 = xpb[base]; xz2 = xpb[base + 256]; xn2 = xpb[base + 512];
    }
    float p0 = 0.f, p1 = 0.f, p2 = 0.f, p3 = 0.f, p4 = 0.f, p5 = 0.f;
    const uint4* hs = ((const uint4*)hsb) + (ks << 3);   // 8 uint4 = 64 fp16
#pragma unroll
    for (int r = 0; r < 8; ++r) {
      uint4 hq = hs[r];                  // uniform addr -> LDS broadcast
      dot2f(p0, hq.x, w[(r << 2) + 0]);
      dot2f(p0, hq.y, w[(r << 2) + 1]);
      dot2f(p0, hq.z, w[(r << 2) + 2]);
      dot2f(p0, hq.w, w[(r << 2) + 3]);
      dot2f(p1, hq.x, w[32 + (r << 2) + 0]);
      dot2f(p1, hq.y, w[32 + (r << 2) + 1]);
      dot2f(p1, hq.z, w[32 + (r << 2) + 2]);
      dot2f(p1, hq.w, w[32 + (r << 2) + 3]);
      dot2f(p2, hq.x, w[64 + (r << 2) + 0]);
      dot2f(p2, hq.y, w[64 + (r << 2) + 1]);
      dot2f(p2, hq.z, w[64 + (r << 2) + 2]);
      dot2f(p2, hq.w, w[64 + (r << 2) + 3]);
      dot2f(p3, hq.x, w[96 + (r << 2) + 0]);
      dot2f(p3, hq.y, w[96 + (r << 2) + 1]);
      dot2f(p3, hq.z, w[96 + (r << 2) + 2]);
      dot2f(p3, hq.w, w[96 + (r << 2) + 3]);
      dot2f(p4, hq.x, w[128 + (r << 2) + 0]);
      dot2f(p4, hq.y, w[128 + (r << 2) + 1]);
      dot2f(p4, hq.z, w[128 + (r << 2) + 2]);
      dot2f(p4, hq.w, w[128 + (r << 2) + 3]);
      dot2f(p5, hq.x, w[160 + (r << 2) + 0]);
      dot2f(p5, hq.y, w[160 + (r << 2) + 1]);
      dot2f(p5, hq.z, w[160 + (r << 2) + 2]);
      dot2f(p5, hq.w, w[160 + (r << 2) + 3]);
    }
    int pb = ks * 776 + og;
    part[pb]       = p0;  part[pb + 128] = p1;
    part[pb + 256] = p2;  part[pb + 384] = p3;
    part[pb + 512] = p4;  part[pb + 640] = p5;
    __syncthreads();                     // partials visible; h reads done
    if (tid < 256) {
      int u = tid;
      float prer = bhr + ((part[u] + part[776 + u]) +
                          (part[1552 + u] + part[2328 + u]));
      float prez = bhz + ((part[256 + u] + part[1032 + u]) +
                          (part[1808 + u] + part[2584 + u]));
      float pren = bhn + ((part[512 + u] + part[1288 + u]) +
                          (part[2064 + u] + part[2840 + u]));
      float r_ = 1.f / (1.f + __expf(-(xr0 + prer)));
      float z_ = 1.f / (1.f + __expf(-(xz0 + prez)));
      float a = xn0 + r_ * pren;
      a = fminf(15.f, fmaxf(-15.f, a));
      float e = __expf(2.f * a);
      float n = (e - 1.f) / (e + 1.f);   // tanh
      float hnew = (1.f - z_) * n + z_ * hold;
      hold = hnew;                       // exact fp32 state in-register
      encb[t * H_ + u] = hnew;
      hsb[u] = f2h(hnew);
      xr0 = xr1; xz0 = xz1; xn0 = xn1;
      xr1 = xr2; xz1 = xz2; xn1 = xn2;
    }
    __syncthreads();                     // new h visible; part consumed
  }
}

// ---------- anchor[b][d] = enc[b,0,:] . W_mx[d] + b_mx[d],  d<2 ----------
__global__ void anchor_kernel(const float* __restrict__ enc,
                              const float* __restrict__ W_mx,
                              const float* __restrict__ b_mx,
                              float* __restrict__ anchor) {
  int tid = threadIdx.x;
  if (tid < 128) {
    int b = tid >> 1, d = tid & 1;
    const float* e = enc + (size_t)b * T_ * H_;    // t = 0 row
    float acc = b_mx[d];
    for (int k = 0; k < 256; ++k) acc += e[k] * W_mx[d * 256 + k];
    anchor[b * 2 + d] = acc;
  }
}

// ---------- heads: enc[16384,256] x WheadT[96,256]^T, k-vectorized ----------
// 384 threads = 4 c-groups x 96; 32 rows/block staged in LDS; W [c][k] float4.
__global__ __launch_bounds__(384) void heads_kernel(
    const float* __restrict__ enc, const float* __restrict__ WheadT,
    const float* __restrict__ b_mz, const float* __restrict__ b_mx,
    const float* __restrict__ b_pz, const float* __restrict__ b_cx,
    const float* __restrict__ anchor,
    float* __restrict__ out_meanz, float* __restrict__ out_meanx,
    float* __restrict__ out_covx, float* __restrict__ stage) {
  __shared__ float el[32 * 256];         // 32 KB
  int tid = threadIdx.x;
  int row0 = blockIdx.x * 32;
  const float4* e4 = (const float4*)(enc + (size_t)row0 * 256);
  float4* el4 = (float4*)el;
#pragma unroll
  for (int i = 0; i < 6; ++i) {
    int idx = i * 384 + tid;             // 2048 float4 = 32x64
    if (idx < 2048) el4[idx] = e4[idx];
  }
  __syncthreads();
  int rg = tid / 96, c = tid - rg * 96;  // rg in [0,4), c in [0,96)
  const float4* Wc = (const float4*)(WheadT + c * 256);
  float acc[8];
#pragma unroll
  for (int r = 0; r < 8; ++r) acc[r] = 0.f;
  for (int k4 = 0; k4 < 64; ++k4) {
    float4 w4 = Wc[k4];
#pragma unroll
    for (int r = 0; r < 8; ++r) {
      float4 ev = el4[(rg * 8 + r) * 64 + k4];
      acc[r] += w4.x * ev.x; acc[r] += w4.y * ev.y;
      acc[r] += w4.z * ev.z; acc[r] += w4.w * ev.w;
    }
  }
#pragma unroll
  for (int r = 0; r < 8; ++r) {
    int row = row0 + rg * 8 + r;
    int bb = row >> 8;
    float a_ = acc[r];
    if (c < 8) {
      out_meanz[(size_t)row * 8 + c] = a_ + b_mz[c];
    } else if (c < 16) {
      int d = c - 8;
      float v = a_ + b_mx[d];
      if (d < 2) v -= anchor[bb * 2 + d];
      out_meanx[(size_t)row * 8 + d] = v;
    } else if (c < 32) {
      int d = c - 16;
      float v = a_ + b_pz[d];
      if (d < 8)                          // diag: softplus (stable)
        v = (v > 0.f) ? (v + log1pf(__expf(-v))) : log1pf(__expf(v));
      stage[(size_t)row * 16 + d] = v;
    } else {
      int d = c - 32;
      out_covx[(size_t)row * 64 + d] = a_ + b_cx[d];
    }
  }
}

// ---------- fused zero + banded scatter: write chol in one pass ----------
__global__ __launch_bounds__(256) void chol_kernel(
    const float* __restrict__ stage, float4* __restrict__ chol) {
  int i = blockIdx.x * 256 + threadIdx.x;
  int stride = gridDim.x * 256;
  for (; i < 8388608; i += stride) {
    int d = i >> 20;                    // latent dim 0..7
    int bt = (i >> 6) & 16383;          // b*256 + t
    int t = bt & 255;
    int lane = i & 63;                  // float4 index within row
    float vd = 0.f, vo = 0.f;
    if ((t >> 2) == lane)        vd = stage[bt * 16 + d];       // diag col t
    if (((t + 1) >> 2) == lane)  vo = stage[bt * 16 + 8 + d];   // off col t+1
    int te = t & 3, oe = (t + 1) & 3;
    float4 v;
    v.x = (te == 0 ? vd : 0.f) + (oe == 0 ? vo : 0.f);
    v.y = (te == 1 ? vd : 0.f) + (oe == 1 ? vo : 0.f);
    v.z = (te == 2 ? vd : 0.f) + (oe == 2 ? vo : 0.f);
    v.w = (te == 3 ? vd : 0.f) + (oe == 3 ? vo : 0.f);
    chol[i] = v;
  }
}

extern "C" void kernel_launch(void* const* d_in, const int* in_sizes, int n_in,
                              void* d_out, int out_size, void* d_ws, size_t ws_size,
                              hipStream_t stream) {
  const float* y    = (const float*)d_in[0];
  const float* W_ih = (const float*)d_in[1];
  const float* W_hh = (const float*)d_in[2];
  const float* b_ih = (const float*)d_in[3];
  const float* b_hh = (const float*)d_in[4];
  const float* W_mz = (const float*)d_in[5];
  const float* b_mz = (const float*)d_in[6];
  const float* W_mx = (const float*)d_in[7];
  const float* b_mx = (const float*)d_in[8];
  const float* W_pz = (const float*)d_in[9];
  const float* b_pz = (const float*)d_in[10];
  const float* W_cx = (const float*)d_in[11];
  const float* b_cx = (const float*)d_in[12];

  float* out    = (float*)d_out;
  float* mean_z = out;                    // [64,256,8]
  float* chol   = out + 131072;           // [8,64,256,256]
  float* mean_x = out + 33685504;         // [16384,8]
  float* cov_x  = out + 33816576;         // [16384,8,8]

  float* ws      = (float*)d_ws;
  float* WT_ih   = ws;                    // 98304
  float* WheadT  = ws + 98304;            // 24576
  unsigned* Wreg = (unsigned*)(ws + 122880); // 98304
  float* anchor  = ws + 221184;           // 128
  float* stage   = ws + 221312;           // 262144

  // large scratch inside the chol output region (overwritten by chol_kernel)
  float* xp  = chol;                      // 12582912 floats
  float* enc = chol + 12582912;           // 4194304 floats

  prep_kernel<<<864, 256, 0, stream>>>(W_ih, W_hh, W_mz, W_mx, W_pz, W_cx,
                                       WT_ih, WheadT, Wreg);
  xproj_kernel<<<512, 256, 0, stream>>>(y, WT_ih, b_ih, xp);
  gru_kernel<<<64, 512, 0, stream>>>(xp, Wreg, b_hh, enc);
  anchor_kernel<<<1, 128, 0, stream>>>(enc, W_mx, b_mx, anchor);
  heads_kernel<<<512, 384, 0, stream>>>(enc, WheadT, b_mz, b_mx, b_pz, b_cx,
                                        anchor, mean_z, mean_x, cov_x, stage);
  chol_kernel<<<8192, 256, 0, stream>>>(stage, (float4*)chol);
}